// Round 1
// baseline (613.812 us; speedup 1.0000x reference)
//
#include <hip/hip_runtime.h>

#define DIM   128
#define BATCH 16384
#define NREL  500
#define CHUNK 16
#define SPLIT 4

// d_ws layout (int32 words):
//   [0,    500)   hist
//   [512,  1013)  off   (NREL+1 exclusive-scan offsets)
//   [1536, 2037)  cur   (scatter cursors)
//   [2048, 2048+BATCH) ids (item indices sorted by relation)

__global__ void zero_k(int* __restrict__ hist) {
    int i = blockIdx.x * 256 + threadIdx.x;
    if (i < NREL) hist[i] = 0;
}

__global__ void hist_k(const int* __restrict__ sample, int* __restrict__ hist) {
    int i = blockIdx.x * 256 + threadIdx.x;
    if (i < BATCH) atomicAdd(&hist[sample[i * 3 + 1]], 1);
}

// single block, 512 threads: exclusive scan of hist[0..NREL) -> off[0..NREL]
__global__ void scan_k(const int* __restrict__ hist, int* __restrict__ off,
                       int* __restrict__ cur) {
    __shared__ int s[512];
    int t = threadIdx.x;
    int orig = (t < NREL) ? hist[t] : 0;
    s[t] = orig;
    __syncthreads();
    #pragma unroll
    for (int d = 1; d < 512; d <<= 1) {
        int x = (t >= d) ? s[t - d] : 0;
        __syncthreads();
        s[t] += x;
        __syncthreads();
    }
    if (t <= NREL) {
        int e = s[t] - orig;          // exclusive prefix
        off[t] = e;
        if (t < NREL) cur[t] = e;
    }
}

__global__ void scat_k(const int* __restrict__ sample, int* __restrict__ cur,
                       int* __restrict__ ids) {
    int i = blockIdx.x * 256 + threadIdx.x;
    if (i < BATCH) {
        int r = sample[i * 3 + 1];
        int p = atomicAdd(&cur[r], 1);
        ids[p] = i;
    }
}

// Grid = NREL*SPLIT. Block (g,sub) handles sub-slice of relation g's sorted items.
// R[g] in registers (64 floats/thread). Items staged CHUNK at a time in LDS,
// norms computed during staging via 32-lane shuffle reduce, main loop ILP-2.
__global__ __launch_bounds__(256, 3)
void score_k(const int* __restrict__ sample, const float* __restrict__ ent,
             const float* __restrict__ rel, const int* __restrict__ off,
             const int* __restrict__ ids, float* __restrict__ out) {
    const int blk = blockIdx.x;
    const int g   = blk >> 2;        // SPLIT == 4
    const int sub = blk & 3;
    const int s0 = off[g], s1 = off[g + 1];
    const int m  = s1 - s0;
    if (m == 0) return;
    const int chunk = (m + SPLIT - 1) >> 2;
    const int lo = s0 + sub * chunk;
    const int hi = min(s1, lo + chunk);
    if (lo >= hi) return;
    const int cnt = hi - lo;

    const int tid  = threadIdx.x;
    const int lane = tid & 63;
    const int wave = tid >> 6;
    const int row  = tid >> 1;       // 0..127: R row owned by this thread
    const int half = tid & 1;        // which 64-col half of the row

    // ---- R[g] into registers: 16 float4 = 64 floats per thread ----
    const float4* __restrict__ R4 = (const float4*)(rel + (size_t)g * (DIM * DIM));
    float4 Rr[16];
    #pragma unroll
    for (int q = 0; q < 16; ++q)
        Rr[q] = R4[row * 32 + half * 16 + q];

    __shared__ alignas(16) float sAT[CHUNK * 2 * DIM]; // raw A,T per item (16 KB)
    __shared__ float sInv[CHUNK * 2];                  // 1/max(||.||,1e-12)
    __shared__ float sRed[CHUNK * 4];                  // per-wave score partials
    __shared__ int   sIds[CHUNK];

    for (int base = 0; base < cnt; base += CHUNK) {
        const int cact = min(CHUNK, cnt - base);

        // ---- stage raw A/T (one item per wave per pass), fuse norm reduce ----
        #pragma unroll
        for (int p = 0; p < 4; ++p) {
            int c = p * 4 + wave;
            if (c < cact) {
                int gi = ids[lo + base + c];
                if (lane == 0) sIds[c] = gi;
                int eidx = (lane < 32) ? sample[gi * 3 + 0] : sample[gi * 3 + 2];
                int e    = (lane & 31) * 4;
                float4 v = *(const float4*)(ent + (size_t)eidx * DIM + e);
                *(float4*)&sAT[c * 256 + (lane < 32 ? 0 : DIM) + e] = v;
                // norm^2 of this 128-float vector across the 32-lane group
                float sq = v.x * v.x + v.y * v.y + v.z * v.z + v.w * v.w;
                #pragma unroll
                for (int o = 16; o > 0; o >>= 1) sq += __shfl_xor(sq, o);
                if ((lane & 31) == 0)
                    sInv[c * 2 + (lane >> 5)] = 1.0f / fmaxf(sqrtf(sq), 1e-12f);
            }
        }
        __syncthreads();

        // ---- main: two items at a time (independent FMA + reduce chains) ----
        for (int c0 = 0; c0 < cact; c0 += 2) {
            const int c1 = (c0 + 1 < cact) ? c0 + 1 : c0;
            const float4* Ta = (const float4*)&sAT[c0 * 256 + DIM + half * 64];
            const float4* Tb = (const float4*)&sAT[c1 * 256 + DIM + half * 64];
            float a0 = 0.f, a1 = 0.f;
            #pragma unroll
            for (int q = 0; q < 16; ++q) {
                float4 ta = Ta[q], tb = Tb[q];
                a0 = fmaf(Rr[q].x, ta.x, a0); a1 = fmaf(Rr[q].x, tb.x, a1);
                a0 = fmaf(Rr[q].y, ta.y, a0); a1 = fmaf(Rr[q].y, tb.y, a1);
                a0 = fmaf(Rr[q].z, ta.z, a0); a1 = fmaf(Rr[q].z, tb.z, a1);
                a0 = fmaf(Rr[q].w, ta.w, a0); a1 = fmaf(Rr[q].w, tb.w, a1);
            }
            float p0 = sAT[c0 * 256 + row] * a0;   // A[row] * partial
            float p1 = sAT[c1 * 256 + row] * a1;
            #pragma unroll
            for (int o = 32; o > 0; o >>= 1) {
                p0 += __shfl_down(p0, o);
                p1 += __shfl_down(p1, o);
            }
            if (lane == 0) {
                sRed[c0 * 4 + wave] = p0;
                if (c1 != c0) sRed[c1 * 4 + wave] = p1;
            }
        }
        __syncthreads();

        // ---- epilogue: combine wave partials, fold 1/norms, write out ----
        if (tid < cact) {
            float s = sRed[tid * 4] + sRed[tid * 4 + 1]
                    + sRed[tid * 4 + 2] + sRed[tid * 4 + 3];
            out[sIds[tid]] = -s * sInv[tid * 2] * sInv[tid * 2 + 1];
        }
        __syncthreads();   // protect sAT/sIds before next chunk
    }
}

extern "C" void kernel_launch(void* const* d_in, const int* in_sizes, int n_in,
                              void* d_out, int out_size, void* d_ws, size_t ws_size,
                              hipStream_t stream) {
    const int*   sample = (const int*)d_in[0];
    const float* ent    = (const float*)d_in[1];
    const float* rel    = (const float*)d_in[2];
    float*       out    = (float*)d_out;
    int*         ws     = (int*)d_ws;

    int* hist = ws;
    int* off  = ws + 512;
    int* cur  = ws + 1536;
    int* ids  = ws + 2048;

    zero_k<<<2, 256, 0, stream>>>(hist);
    hist_k<<<BATCH / 256, 256, 0, stream>>>(sample, hist);
    scan_k<<<1, 512, 0, stream>>>(hist, off, cur);
    scat_k<<<BATCH / 256, 256, 0, stream>>>(sample, cur, ids);
    score_k<<<NREL * SPLIT, 256, 0, stream>>>(sample, ent, rel, off, ids, out);
}